// Round 4
// baseline (72.060 us; speedup 1.0000x reference)
//
#include <hip/hip_runtime.h>
#include <stdint.h>

#define HH 224
#define WW 224
#define NSEAM 7
#define BWIDTH 5
#define NP 11
#define BB 256
#define KK 64
#define YCH 4
#define YROWS (HH / YCH)

// DPP helpers (ctrl must be literal): row_shr:1=0x111 (dst[i]=src[i-1]),
// row_shl:1=0x101 (dst[i]=src[i+1]), row_ror:N=0x120+N. Rows = 16 lanes.
#define DPPF_OLD(old, src, ctrl) \
    __int_as_float(__builtin_amdgcn_update_dpp(__float_as_int(old), __float_as_int(src), ctrl, 0xF, 0xF, false))
#define DPPF_Z(src, ctrl) \
    __int_as_float(__builtin_amdgcn_update_dpp(0, __float_as_int(src), ctrl, 0xF, 0xF, true))
#define DPPI_Z(src, ctrl) \
    __builtin_amdgcn_update_dpp(0, (int)(src), ctrl, 0xF, 0xF, true)

// ---------------------------------------------------------------------------
// Kernel 0: cache-warm pre-pass + gacc zero. One block per (image, seam-band).
// Touches exactly the lines dp_kernel will read, with massive MLP so it runs
// at BW; dp's loads then hit L2/L3 (~200-500cy) instead of HBM (~900cy).
// ---------------------------------------------------------------------------
__global__ __launch_bounds__(256) void warm_kernel(const float* __restrict__ g,
                                                   unsigned long long* __restrict__ gacc) {
    int tid = blockIdx.x * 256 + threadIdx.x;
    if (tid < BB * KK) gacc[tid] = 0ull;

    int b = blockIdx.x / NSEAM;
    int p = blockIdx.x % NSEAM;
    const float* gb = g + (size_t)b * HH * WW;
    int r0 = 28 * (p + 1) - BWIDTH;          // band base (row for dir1, col for dir0)

    float4 a4 = {0.f, 0.f, 0.f, 0.f};
    // dir1 band: rows r0..r0+10, full width -> 11*224/4 = 616 float4 (contig)
    const float4* rowbase = (const float4*)(gb + (size_t)r0 * WW);
    for (int i = threadIdx.x; i < 11 * WW / 4; i += 256) {
        float4 v = rowbase[i];
        a4.x += v.x; a4.y += v.y; a4.z += v.z; a4.w += v.w;
    }
    // dir0 band: cols r0..r0+10, all rows; aligned 16-float window covers it
    int cA = r0 & ~3;
    for (int i = threadIdx.x; i < HH * 4; i += 256) {
        int r = i >> 2, q = i & 3;
        float4 v = *(const float4*)(gb + (size_t)r * WW + cA + 4 * q);
        a4.x += v.x; a4.y += v.y; a4.z += v.z; a4.w += v.w;
    }
    float s = a4.x + a4.y + a4.z + a4.w;
    asm volatile("" :: "v"(s));              // keep loads alive (rule #17)
}

// ---------------------------------------------------------------------------
// Kernel 1: seam DP, 16 lanes per DP (lane j = band position j, 11 active).
// 3584 DPs -> 224 blocks x 256 threads. Depth-3 prefetch (4 static buffers).
// cost chain via v_min (4-op dependent chain); selector derived OFF-path by
// equality compares in reference candidate order [jm, j, jp] (first-min,
// strict <, incl. j==0 / j==10 clamp semantics). Backtrack via 2-bit codes.
// ---------------------------------------------------------------------------
__global__ __launch_bounds__(256) void dp_kernel(const float* __restrict__ g,
                                                 int* __restrict__ paths) {
    __shared__ uint32_t ch[16][226];   // packed 2-bit sels, 11 lanes per word
    __shared__ int      pth[16][226];  // backtracked path positions

    const int j   = threadIdx.x & 15;
    const int grp = threadIdx.x >> 4;
    const int gid = blockIdx.x * 16 + grp;      // (b, dir, seam)
    const int b   = gid / 14;
    const int s   = gid % 14;
    const int dir = s / 7;
    const int p   = s % 7;
    const int band0 = 28 * (p + 1) - BWIDTH;
    const int rs = (dir == 0) ? WW : 1;         // step-axis stride
    const int cs = (dir == 0) ? 1 : WW;         // band-axis stride
    const int jc = (j > 10) ? 10 : j;           // clamp junk lanes' loads
    const float* gptr = g + (size_t)b * HH * WW + (size_t)(band0 + jc) * cs;

    const int jj2  = 2 * j;                     // shift for sel packing
    const int sel0 = (j == 0) ? 1 : 0;          // sel when jm candidate wins

    float gbuf[4][16];
    float cost = 0.0f;

#define LOADC(c)                                                            \
    _Pragma("unroll")                                                       \
    for (int rr = 0; rr < 16; ++rr) gbuf[(c) % 4][rr] = gptr[((c) * 16 + rr) * rs];

#define PROCC(c)                                                            \
    _Pragma("unroll")                                                       \
    for (int rr = 0; rr < 16; ++rr) {                                       \
        if (rr == 0 && (c) == 0) {                                          \
            cost = -gbuf[0][0];                                             \
        } else {                                                            \
            float pm  = DPPF_OLD(cost, cost, 0x111); /* prev[j-1], lane0 keeps old */    \
            float ppv = DPPF_OLD(cost, cost, 0x101); /* prev[j+1], lane15 keeps old */   \
            ppv = (j >= 10) ? cost : ppv;            /* clip at j=10 */                  \
            float best = fminf(fminf(pm, cost), ppv);                       \
            int sel = (pm == best) ? sel0 : ((cost == best) ? 1 : 2);       \
            cost = best - gbuf[(c) % 4][rr];                                \
            uint32_t u = (uint32_t)sel << jj2;                              \
            u |= (uint32_t)DPPI_Z(u, 0x128);                                \
            u |= (uint32_t)DPPI_Z(u, 0x124);                                \
            u |= (uint32_t)DPPI_Z(u, 0x122);                                \
            u |= (uint32_t)DPPI_Z(u, 0x121);                                \
            if (j == 0) ch[grp][(c) * 16 + rr] = u;                         \
        }                                                                   \
    }

    LOADC(0);
    LOADC(1);
    LOADC(2);
#pragma unroll
    for (int c = 0; c < 14; ++c) {
        if (c + 3 < 14) LOADC(c + 3);
        PROCC(c);
    }

    // final argmin across 11 lanes, first-min tie-break == lexicographic min
    float rc = (j <= 10) ? cost : INFINITY;
    int   ri = (j <= 10) ? j : 15;
#define REDSTEP(ctrl)                                                        \
    {                                                                        \
        float oc = DPPF_Z(rc, ctrl);                                         \
        int   oi = DPPI_Z(ri, ctrl);                                         \
        bool t = (oc < rc) || (oc == rc && oi < ri);                         \
        rc = t ? oc : rc; ri = t ? oi : ri;                                  \
    }
    REDSTEP(0x128) REDSTEP(0x124) REDSTEP(0x122) REDSTEP(0x121)

    int pos = ri;
    if (j == 0) pth[grp][HH - 1] = band0 + pos;

    // backtrack: uniform (broadcast) LDS reads issued ahead; chain ~3 VALU/row
    for (int c = 13; c >= 0; --c) {
        uint32_t w[16];
#pragma unroll
        for (int rr = 0; rr < 16; ++rr) w[rr] = ch[grp][c * 16 + rr];
#pragma unroll
        for (int rr = 15; rr >= 0; --rr) {
            int r = c * 16 + rr;
            if (r >= 1) {
                int sel = (int)((w[rr] >> (2 * pos)) & 3u);
                pos += sel - 1;
                if (j == 0) pth[grp][r - 1] = band0 + pos;
            }
        }
    }

    int* op = paths + (size_t)gid * HH;
#pragma unroll
    for (int c = 0; c < 14; ++c) op[c * 16 + j] = pth[grp][c * 16 + j];

#undef LOADC
#undef PROCC
#undef REDSTEP
}

// ---------------------------------------------------------------------------
// Kernel 2: labels + centroid partials. Grid = B*4 (4 y-chunks per image).
// Thread = column; run-length flush -> packed u64 LDS atomic per run; block
// partials -> global atomicAdd. Fields: [42..63]=cnt, [21..41]=sum_y,
// [0..20]=sum_x; per-region totals < field capacity, u64 adds carry-free,
// all values integers < 2^22 exact in f32 -> division matches JAX bitwise.
// ---------------------------------------------------------------------------
__global__ __launch_bounds__(256) void label_kernel(const int* __restrict__ paths,
                                                    float* __restrict__ out,
                                                    unsigned long long* __restrict__ gacc) {
    const int b  = blockIdx.x >> 2;
    const int y0 = (blockIdx.x & 3) * YROWS;
    const int y1 = y0 + YROWS;

    __shared__ int vpc[NSEAM][YROWS];
    __shared__ unsigned long long acc[KK];

    const int* pb = paths + (size_t)b * 14 * HH;
    for (int i = threadIdx.x; i < NSEAM * YROWS; i += 256) {
        int q = i / YROWS, r = i - q * YROWS;
        vpc[q][r] = pb[q * HH + y0 + r];
    }
    if (threadIdx.x < KK) acc[threadIdx.x] = 0ull;
    __syncthreads();

    const int x = threadIdx.x;
    if (x < WW) {
        int hx[NSEAM];
#pragma unroll
        for (int q = 0; q < NSEAM; ++q) hx[q] = pb[(NSEAM + q) * HH + x];

        float* mb = out + (size_t)BB * KK * 2 + (size_t)b * HH * WW;
        int cur = -1, ys = y0;
        for (int y = y0; y < y1; ++y) {
            int vl = 0, hl = 0;
#pragma unroll
            for (int q = 0; q < NSEAM; ++q) {
                vl += (vpc[q][y - y0] <= x) ? 1 : 0;
                hl += (hx[q] <= y) ? 1 : 0;
            }
            int lab = vl + 8 * hl;
            mb[y * WW + x] = (float)lab;
            if (lab != cur) {
                if (cur >= 0) {
                    unsigned cnt = (unsigned)(y - ys);
                    unsigned sy  = (unsigned)((ys + y - 1) * (y - ys) / 2);
                    unsigned sx  = (unsigned)x * cnt;
                    atomicAdd(&acc[cur], ((unsigned long long)cnt << 42) |
                                         ((unsigned long long)sy << 21) |
                                         (unsigned long long)sx);
                }
                cur = lab; ys = y;
            }
        }
        {
            unsigned cnt = (unsigned)(y1 - ys);
            unsigned sy  = (unsigned)((ys + y1 - 1) * (y1 - ys) / 2);
            unsigned sx  = (unsigned)x * cnt;
            atomicAdd(&acc[cur], ((unsigned long long)cnt << 42) |
                                 ((unsigned long long)sy << 21) |
                                 (unsigned long long)sx);
        }
    }
    __syncthreads();

    if (threadIdx.x < KK) {
        unsigned long long v = acc[threadIdx.x];
        if (v) atomicAdd(&gacc[(size_t)b * KK + threadIdx.x], v);
    }
}

// ---------------------------------------------------------------------------
// Kernel 3: finalize centroids. 16384 regions; unpack, divide, float2 store.
// ---------------------------------------------------------------------------
__global__ __launch_bounds__(256) void finalize_kernel(const unsigned long long* __restrict__ gacc,
                                                       float* __restrict__ out) {
    int i = blockIdx.x * 256 + threadIdx.x;    // < BB*KK
    unsigned long long sv = gacc[i];
    float cnt = (float)(unsigned)(sv >> 42);
    float sy  = (float)(unsigned)((sv >> 21) & 0x1FFFFFu);
    float sx  = (float)(unsigned)(sv & 0x1FFFFFu);
    float c = fmaxf(cnt, 1e-6f);
    float2 r; r.x = sy / c; r.y = sx / c;
    *reinterpret_cast<float2*>(out + (size_t)i * 2) = r;
}

extern "C" void kernel_launch(void* const* d_in, const int* in_sizes, int n_in,
                              void* d_out, int out_size, void* d_ws, size_t ws_size,
                              hipStream_t stream) {
    const float* g = (const float*)d_in[1];
    float* out = (float*)d_out;
    int* paths = (int*)d_ws;                                   // 3,211,264 B
    unsigned long long* gacc =
        (unsigned long long*)((char*)d_ws + (size_t)BB * 14 * HH * 4);  // 128 KiB

    warm_kernel<<<BB * NSEAM, 256, 0, stream>>>(g, gacc);
    dp_kernel<<<(BB * 14) / 16, 256, 0, stream>>>(g, paths);
    label_kernel<<<BB * YCH, 256, 0, stream>>>(paths, out, gacc);
    finalize_kernel<<<(BB * KK) / 256, 256, 0, stream>>>(gacc, out);
}

// Round 5
// 61.850 us; speedup vs baseline: 1.1651x; 1.1651x over previous
//
#include <hip/hip_runtime.h>
#include <stdint.h>

#define HH 224
#define WW 224
#define NSEAM 7
#define BWIDTH 5
#define NP 11
#define BB 256
#define KK 64
#define YCH 4
#define YROWS (HH / YCH)

// DPP helpers (ctrl must be literal): row_shr:1=0x111 (dst[i]=src[i-1]),
// row_shl:1=0x101 (dst[i]=src[i+1]), row_ror:N=0x120+N. Rows = 16 lanes.
#define DPPF_OLD(old, src, ctrl) \
    __int_as_float(__builtin_amdgcn_update_dpp(__float_as_int(old), __float_as_int(src), ctrl, 0xF, 0xF, false))
#define DPPF_Z(src, ctrl) \
    __int_as_float(__builtin_amdgcn_update_dpp(0, __float_as_int(src), ctrl, 0xF, 0xF, true))
#define DPPI_Z(src, ctrl) \
    __builtin_amdgcn_update_dpp(0, (int)(src), ctrl, 0xF, 0xF, true)

// ---------------------------------------------------------------------------
// Kernel 1: seam DP, 16 lanes per DP (lane j = band position j, 11 active).
// Dir-major gid mapping: gid = dir*1792 + b*7 + p  -> dir is BLOCK-uniform.
//   dir0 (blocks 0..111):  direct loads, lane j = column band0+j (coalesced).
//   dir1 (blocks 112..223): coalesced row-segment loads (lane j = column,
//     11 rows) double-buffered through padded LDS tile [11][17], read
//     transposed -> kills the 896B-stride / 44-lines-per-load pattern.
// Exact reference semantics preserved: candidates [jm, j, jp], strict-<
// first-min (via fminf + equality compares in candidate order), final argmin
// first-min, backtrack via 2-bit codes. Also zeroes gacc for label kernel.
// ---------------------------------------------------------------------------
__global__ __launch_bounds__(256) void dp_kernel(const float* __restrict__ g,
                                                 int* __restrict__ paths,
                                                 unsigned long long* __restrict__ gacc) {
    __shared__ uint32_t ch[16][226];      // packed 2-bit sels, 11 lanes/word
    __shared__ int      pth[16][226];     // backtracked path positions
    __shared__ float    tileD[16][2][11 * 17];  // dir1 staging, padded

    {   // zero global centroid accumulators (label kernel runs after us)
        int tid = blockIdx.x * 256 + threadIdx.x;
        if (tid < BB * KK) gacc[tid] = 0ull;
    }

    const int j   = threadIdx.x & 15;
    const int grp = threadIdx.x >> 4;
    const int gid = blockIdx.x * 16 + grp;
    const int dir = gid / (BB * NSEAM);         // block-uniform (1792/16=112)
    const int rem = gid - dir * (BB * NSEAM);
    const int b   = rem / NSEAM;
    const int p   = rem - b * NSEAM;
    const int band0 = 28 * (p + 1) - BWIDTH;
    const int jc = (j > 10) ? 10 : j;           // clamp junk lanes
    const int jd = jc;                          // clamped LDS read row

    const int jj2  = 2 * j;
    const int sel0 = (j == 0) ? 1 : 0;          // sel when jm candidate wins

    const float* gb = g + (size_t)b * HH * WW;
    float cost = 0.0f;

#define PROCC(BUF, c)                                                       \
    _Pragma("unroll")                                                       \
    for (int rr = 0; rr < 16; ++rr) {                                       \
        if (rr == 0 && (c) == 0) {                                          \
            cost = -(BUF)[0];                                               \
        } else {                                                            \
            float pm  = DPPF_OLD(cost, cost, 0x111); /* prev[j-1], lane0 keeps own */  \
            float ppv = DPPF_OLD(cost, cost, 0x101); /* prev[j+1], lane15 keeps own */ \
            ppv = (j >= 10) ? cost : ppv;            /* clip at j=10 */                \
            float best = fminf(fminf(pm, cost), ppv);                       \
            int sel = (pm == best) ? sel0 : ((cost == best) ? 1 : 2);       \
            cost = best - (BUF)[rr];                                        \
            uint32_t u = (uint32_t)sel << jj2;                              \
            u |= (uint32_t)DPPI_Z(u, 0x128);                                \
            u |= (uint32_t)DPPI_Z(u, 0x124);                                \
            u |= (uint32_t)DPPI_Z(u, 0x122);                                \
            u |= (uint32_t)DPPI_Z(u, 0x121);                                \
            if (j == 0) ch[grp][(c) * 16 + rr] = u;                         \
        }                                                                   \
    }

    if (dir == 0) {
        // lane j = column band0+jc; rows advance -> coalesced within group
        const float* gptr = gb + band0 + jc;
        float gbuf[3][16];
#define LOADC(c)                                                            \
    _Pragma("unroll")                                                       \
    for (int rr = 0; rr < 16; ++rr) gbuf[(c) % 3][rr] = gptr[((c) * 16 + rr) * WW];
        LOADC(0);
        LOADC(1);
#pragma unroll
        for (int c = 0; c < 14; ++c) {
            if (c + 2 < 14) LOADC(c + 2);
            PROCC(gbuf[(c) % 3], c);
        }
#undef LOADC
    } else {
        // lane j = column offset within 16-col chunk; 11 coalesced row loads
        const float* gcol = gb + (size_t)band0 * WW + j;
        float rA[11], rB[11], tb[16];
#define LOADR(SET, c)                                                       \
    _Pragma("unroll")                                                       \
    for (int q = 0; q < 11; ++q) SET[q] = gcol[(size_t)q * WW + (c) * 16];
#define WRITET(BUF, SET)                                                    \
    _Pragma("unroll")                                                       \
    for (int q = 0; q < 11; ++q) tileD[grp][BUF][q * 17 + j] = SET[q];
#define READT(BUF)                                                          \
    _Pragma("unroll")                                                       \
    for (int rr = 0; rr < 16; ++rr) tb[rr] = tileD[grp][BUF][jd * 17 + rr];

        LOADR(rA, 0);
        WRITET(0, rA);
        LOADR(rB, 1);
        __syncthreads();
#pragma unroll
        for (int c = 0; c < 14; ++c) {
            if (c + 2 < 14) {                    // prefetch chunk c+2 into free set
                if (c & 1) { LOADR(rB, c + 2); } else { LOADR(rA, c + 2); }
            }
            if (c + 1 < 14) {                    // stage chunk c+1 (in other set)
                if (c & 1) { WRITET(0, rA); } else { WRITET(1, rB); }
            }
            READT(c & 1);
            PROCC(tb, c);
            __syncthreads();
        }
#undef LOADR
#undef WRITET
#undef READT
    }

    // final argmin across 11 lanes, first-min tie-break == lexicographic min
    float rc = (j <= 10) ? cost : INFINITY;
    int   ri = (j <= 10) ? j : 15;
#define REDSTEP(ctrl)                                                        \
    {                                                                        \
        float oc = DPPF_Z(rc, ctrl);                                         \
        int   oi = DPPI_Z(ri, ctrl);                                         \
        bool t = (oc < rc) || (oc == rc && oi < ri);                         \
        rc = t ? oc : rc; ri = t ? oi : ri;                                  \
    }
    REDSTEP(0x128) REDSTEP(0x124) REDSTEP(0x122) REDSTEP(0x121)
#undef REDSTEP

    int pos = ri;
    if (j == 0) pth[grp][HH - 1] = band0 + pos;

    // backtrack: uniform (broadcast) LDS reads issued ahead; chain ~3 VALU/row
    for (int c = 13; c >= 0; --c) {
        uint32_t w[16];
#pragma unroll
        for (int rr = 0; rr < 16; ++rr) w[rr] = ch[grp][c * 16 + rr];
#pragma unroll
        for (int rr = 15; rr >= 0; --rr) {
            int r = c * 16 + rr;
            if (r >= 1) {
                int sel = (int)((w[rr] >> (2 * pos)) & 3u);
                pos += sel - 1;
                if (j == 0) pth[grp][r - 1] = band0 + pos;
            }
        }
    }

    int* op = paths + (size_t)(b * 14 + dir * NSEAM + p) * HH;
#pragma unroll
    for (int c = 0; c < 14; ++c) op[c * 16 + j] = pth[grp][c * 16 + j];

#undef PROCC
}

// ---------------------------------------------------------------------------
// Kernel 2: labels + centroid partials. Grid = B*4 (4 y-chunks per image).
// Thread = column; run-length flush -> packed u64 LDS atomic per run; block
// partials -> global atomicAdd. Fields: [42..63]=cnt, [21..41]=sum_y,
// [0..20]=sum_x; per-region totals < field capacity, u64 adds carry-free,
// all values integers < 2^22 exact in f32 -> division matches JAX bitwise.
// ---------------------------------------------------------------------------
__global__ __launch_bounds__(256) void label_kernel(const int* __restrict__ paths,
                                                    float* __restrict__ out,
                                                    unsigned long long* __restrict__ gacc) {
    const int b  = blockIdx.x >> 2;
    const int y0 = (blockIdx.x & 3) * YROWS;
    const int y1 = y0 + YROWS;

    __shared__ int vpc[NSEAM][YROWS];
    __shared__ unsigned long long acc[KK];

    const int* pb = paths + (size_t)b * 14 * HH;
    for (int i = threadIdx.x; i < NSEAM * YROWS; i += 256) {
        int q = i / YROWS, r = i - q * YROWS;
        vpc[q][r] = pb[q * HH + y0 + r];
    }
    if (threadIdx.x < KK) acc[threadIdx.x] = 0ull;
    __syncthreads();

    const int x = threadIdx.x;
    if (x < WW) {
        int hx[NSEAM];
#pragma unroll
        for (int q = 0; q < NSEAM; ++q) hx[q] = pb[(NSEAM + q) * HH + x];

        float* mb = out + (size_t)BB * KK * 2 + (size_t)b * HH * WW;
        int cur = -1, ys = y0;
        for (int y = y0; y < y1; ++y) {
            int vl = 0, hl = 0;
#pragma unroll
            for (int q = 0; q < NSEAM; ++q) {
                vl += (vpc[q][y - y0] <= x) ? 1 : 0;
                hl += (hx[q] <= y) ? 1 : 0;
            }
            int lab = vl + 8 * hl;
            mb[y * WW + x] = (float)lab;
            if (lab != cur) {
                if (cur >= 0) {
                    unsigned cnt = (unsigned)(y - ys);
                    unsigned sy  = (unsigned)((ys + y - 1) * (y - ys) / 2);
                    unsigned sx  = (unsigned)x * cnt;
                    atomicAdd(&acc[cur], ((unsigned long long)cnt << 42) |
                                         ((unsigned long long)sy << 21) |
                                         (unsigned long long)sx);
                }
                cur = lab; ys = y;
            }
        }
        {
            unsigned cnt = (unsigned)(y1 - ys);
            unsigned sy  = (unsigned)((ys + y1 - 1) * (y1 - ys) / 2);
            unsigned sx  = (unsigned)x * cnt;
            atomicAdd(&acc[cur], ((unsigned long long)cnt << 42) |
                                 ((unsigned long long)sy << 21) |
                                 (unsigned long long)sx);
        }
    }
    __syncthreads();

    if (threadIdx.x < KK) {
        unsigned long long v = acc[threadIdx.x];
        if (v) atomicAdd(&gacc[(size_t)b * KK + threadIdx.x], v);
    }
}

// ---------------------------------------------------------------------------
// Kernel 3: finalize centroids. 16384 regions; unpack, divide, float2 store.
// ---------------------------------------------------------------------------
__global__ __launch_bounds__(256) void finalize_kernel(const unsigned long long* __restrict__ gacc,
                                                       float* __restrict__ out) {
    int i = blockIdx.x * 256 + threadIdx.x;    // < BB*KK
    unsigned long long sv = gacc[i];
    float cnt = (float)(unsigned)(sv >> 42);
    float sy  = (float)(unsigned)((sv >> 21) & 0x1FFFFFu);
    float sx  = (float)(unsigned)(sv & 0x1FFFFFu);
    float c = fmaxf(cnt, 1e-6f);
    float2 r; r.x = sy / c; r.y = sx / c;
    *reinterpret_cast<float2*>(out + (size_t)i * 2) = r;
}

extern "C" void kernel_launch(void* const* d_in, const int* in_sizes, int n_in,
                              void* d_out, int out_size, void* d_ws, size_t ws_size,
                              hipStream_t stream) {
    const float* g = (const float*)d_in[1];
    float* out = (float*)d_out;
    int* paths = (int*)d_ws;                                   // 3,211,264 B
    unsigned long long* gacc =
        (unsigned long long*)((char*)d_ws + (size_t)BB * 14 * HH * 4);  // 128 KiB

    dp_kernel<<<(BB * 14) / 16, 256, 0, stream>>>(g, paths, gacc);
    label_kernel<<<BB * YCH, 256, 0, stream>>>(paths, out, gacc);
    finalize_kernel<<<(BB * KK) / 256, 256, 0, stream>>>(gacc, out);
}